// Round 6
// baseline (1325.559 us; speedup 1.0000x reference)
//
#include <hip/hip_runtime.h>
#include <stdint.h>
#include <math.h>

// Autoregressive LSTM controller. B=4096, EMB=128, HID=512, OUT=64, STEPS=20.
// Round 6: counted-vmcnt 8-phase pipeline (T3/T4), A-prefetch in regs (T14),
// setprio around MFMA (T5), 8B-granule row&15 LDS swizzle (R4's zero-conflict
// pattern), 256 blocks x 8 waves (halves W staging), zh flag removes memsets.

#define B_SZ  4096
#define EMB   128
#define HID   512
#define NOUT  64
#define STEPS 20
#define G4    2048
#define HF    ((size_t)B_SZ * HID)   // elems per hi/lo plane of h

typedef __attribute__((ext_vector_type(8)))  short bf16x8;
typedef __attribute__((ext_vector_type(16))) float f32x16;

union B8 { uint2 q[2]; bf16x8 v; };

// ---------------- threefry2x32 (JAX partitionable semantics) ----------------
__device__ __forceinline__ void tf2x32(uint32_t k0, uint32_t k1,
                                       uint32_t x0, uint32_t x1,
                                       uint32_t& o0, uint32_t& o1) {
  const uint32_t ks2 = k0 ^ k1 ^ 0x1BD11BDAu;
#define TFR(r) { x0 += x1; x1 = (x1 << (r)) | (x1 >> (32 - (r))); x1 ^= x0; }
  x0 += k0; x1 += k1;
  TFR(13) TFR(15) TFR(26) TFR(6)
  x0 += k1;  x1 += ks2 + 1u;
  TFR(17) TFR(29) TFR(16) TFR(24)
  x0 += ks2; x1 += k0 + 2u;
  TFR(13) TFR(15) TFR(26) TFR(6)
  x0 += k0;  x1 += k1 + 3u;
  TFR(17) TFR(29) TFR(16) TFR(24)
  x0 += k1;  x1 += ks2 + 4u;
  TFR(13) TFR(15) TFR(26) TFR(6)
  x0 += ks2; x1 += k0 + 5u;
#undef TFR
  o0 = x0; o1 = x1;
}

// RNE split of fp32 into bf16 hi + bf16 lo
__device__ __forceinline__ void bf16split(float f, ushort& hi, ushort& lo) {
  uint32_t u = __float_as_uint(f);
  uint32_t r = u + 0x7fffu + ((u >> 16) & 1u);
  hi = (ushort)(r >> 16);
  float fh = __uint_as_float((r >> 16) << 16);
  float fl = f - fh;
  uint32_t v = __float_as_uint(fl);
  uint32_t r2 = v + 0x7fffu + ((v >> 16) & 1u);
  lo = (ushort)(r2 >> 16);
}

__device__ __forceinline__ void gload_lds16(const ushort* g, ushort* d) {
  __builtin_amdgcn_global_load_lds(
      (const __attribute__((address_space(1))) void*)g,
      (__attribute__((address_space(3))) void*)d, 16, 0, 0);
}

// ---------------- E_proj = emb @ W_ih.T + b_ih + b_hh (fp32, once) ----------
__global__ __launch_bounds__(256) void eproj_kernel(
    const float* __restrict__ emb, const float* __restrict__ W_ih,
    const float* __restrict__ b_ih, const float* __restrict__ b_hh,
    float* __restrict__ E) {
  const int t = blockIdx.x;
  __shared__ float es[EMB];
  for (int k = threadIdx.x; k < EMB; k += blockDim.x) es[k] = emb[t * EMB + k];
  __syncthreads();
  for (int j = threadIdx.x; j < G4; j += blockDim.x) {
    const float* w = W_ih + (size_t)j * EMB;
    float acc = 0.f;
#pragma unroll 8
    for (int k = 0; k < EMB; k += 4) {
      float4 wv = *(const float4*)(w + k);
      acc += wv.x * es[k] + wv.y * es[k + 1] + wv.z * es[k + 2] + wv.w * es[k + 3];
    }
    E[(size_t)t * G4 + j] = acc + b_ih[j] + b_hh[j];
  }
}

// ---------------- W_hh -> pre-swizzled staging mirror (once) ----------------
// Layout: [ub(16)][kt(8)][plane(2)][row(128)][e(64)], 4-elem (8B) granule
// swizzle: position e holds W[grow][kt*64 + (e ^ ((row&15)<<2))].
__global__ __launch_bounds__(256) void wprep_whh(
    const float* __restrict__ W_hh, ushort* __restrict__ wswz) {
  const int id = blockIdx.x * 256 + threadIdx.x;   // 1024 blocks -> 262144 chunks
  const int ub    = id >> 14;
  const int w14   = id & 16383;
  const int kt    = w14 >> 11;
  const int plane = (w14 >> 10) & 1;
  const int row   = (w14 >> 3) & 127;
  const int ec    = w14 & 7;
  const int grow = (row >> 5) * HID + ub * 32 + (row & 31);
  const int swz = (row & 15) << 2;
  ushort vals[8];
#pragma unroll
  for (int j = 0; j < 8; ++j) {
    const int e = ec * 8 + j;
    const int k = kt * 64 + (e ^ swz);
    ushort hi, lo;
    bf16split(W_hh[(size_t)grow * HID + k], hi, lo);
    vals[j] = plane ? lo : hi;
  }
  *(uint4*)(wswz + (size_t)id * 8) = *(const uint4*)vals;
}

// ---------------- W_lin -> coalesced transpose [k4][o][4] (once) ------------
__global__ __launch_bounds__(256) void wprep_lin(
    const float* __restrict__ W_lin, float* __restrict__ wlt) {
  const int id = blockIdx.x * 256 + threadIdx.x;   // 128 blocks -> 32768
  const int j = id & 3, o = (id >> 2) & 63, k4 = id >> 8;
  wlt[id] = W_lin[(size_t)o * HID + k4 * 4 + j];
}

// ---------------- fused MFMA gates GEMM + LSTM cell ----------------
// 256 blocks x 512 thr (8 waves); wave = 32 rows x 32 units x 4 sections.
// 8-phase unrolled K loop, counted vmcnt(8): stage loads drained at barrier,
// A-prefetch loads stay in flight across it.
__global__ __launch_bounds__(512, 2) void lstm_step_mfma(
    const ushort* __restrict__ hf,     // [2][frag-major B x HID]
    float*        __restrict__ c,      // [B][HID] fp32 in-place
    float*        __restrict__ h_out,  // [B][HID] fp32 (logits input)
    ushort*       __restrict__ hf_out, // [2][frag-major]
    const ushort* __restrict__ wswz,   // pre-swizzled W mirror
    const float*  __restrict__ E,      // [64][2048]
    const int*    __restrict__ tok,    // [B]
    int zh)                            // 1: h==0 (step 0) -> skip GEMM & c read
{
  __shared__ ushort Bt[2][16384];      // 2 x 32 KB double buffer (both planes)
  const int tid = threadIdx.x;
  const int w = tid >> 6, l = tid & 63;
  const int l31 = l & 31, lh = l >> 5;

  // XCD-aware decode: xcd = raw%8 owns 4 ub x 8 mb tiles
  const int raw = blockIdx.x;
  const int x = raw & 7, j = raw >> 3;
  const int ub  = (x & 3) * 4 + (j & 3);
  const int mbi = (x >> 2) * 8 + (j >> 2);
  const int m0 = mbi * 256 + w * 32;
  const int u0 = ub * 32;

  f32x16 acc[4] = {};

  const size_t abase = ((size_t)(m0 >> 5) * 64 + lh) * 256 + (size_t)l31 * 8;
  const ushort* a0 = hf + abase;
  const ushort* a1 = hf + HF + abase;
  const ushort* wsrc = wswz + (size_t)ub * 131072 + (size_t)(w * 512 + l * 8);

  if (!zh) {
    bf16x8 Aa0[4], Aa1[4], Ab0[4], Ab1[4];

#define SB0 __builtin_amdgcn_sched_barrier(0)
#define STAGE(KT, BUF) { \
  _Pragma("unroll") \
  for (int r = 0; r < 4; ++r) \
    gload_lds16(wsrc + (size_t)(KT) * 16384 + r * 4096, &Bt[BUF][w * 512 + r * 4096]); }
#define LOADA(KT, A0v, A1v) { \
  _Pragma("unroll") \
  for (int kc = 0; kc < 4; ++kc) { \
    const size_t ko = (size_t)((KT) * 8 + kc * 2) * 256; \
    A0v[kc] = *(const bf16x8*)(a0 + ko); \
    A1v[kc] = *(const bf16x8*)(a1 + ko); } }
#define COMPUTE(BUF, A0v, A1v) { \
  __builtin_amdgcn_s_setprio(1); \
  _Pragma("unroll") \
  for (int kc = 0; kc < 4; ++kc) { \
    _Pragma("unroll") \
    for (int s = 0; s < 4; ++s) { \
      const int row = s * 32 + l31; \
      const int swz = (row & 15) << 2; \
      const int eb = kc * 16 + lh * 8; \
      const ushort* rb = &Bt[BUF][row * 64]; \
      B8 uh, ul; \
      uh.q[0] = *(const uint2*)(rb + ((eb)     ^ swz)); \
      uh.q[1] = *(const uint2*)(rb + ((eb + 4) ^ swz)); \
      ul.q[0] = *(const uint2*)(rb + 8192 + ((eb)     ^ swz)); \
      ul.q[1] = *(const uint2*)(rb + 8192 + ((eb + 4) ^ swz)); \
      acc[s] = __builtin_amdgcn_mfma_f32_32x32x16_bf16(A0v[kc], uh.v, acc[s], 0, 0, 0); \
      acc[s] = __builtin_amdgcn_mfma_f32_32x32x16_bf16(A1v[kc], uh.v, acc[s], 0, 0, 0); \
      acc[s] = __builtin_amdgcn_mfma_f32_32x32x16_bf16(A0v[kc], ul.v, acc[s], 0, 0, 0); } } \
  __builtin_amdgcn_s_setprio(0); }
#define FENCE8 { asm volatile("s_waitcnt vmcnt(8)" ::: "memory"); SB0; \
                 __builtin_amdgcn_s_barrier(); }

    // prologue: stage kt0, load A(kt0)
    STAGE(0, 0); SB0; LOADA(0, Aa0, Aa1); SB0;
    FENCE8;
    // kt=0
    STAGE(1, 1); SB0; LOADA(1, Ab0, Ab1); SB0;
    COMPUTE(0, Aa0, Aa1); FENCE8;
    // kt=1
    STAGE(2, 0); SB0; LOADA(2, Aa0, Aa1); SB0;
    COMPUTE(1, Ab0, Ab1); FENCE8;
    // kt=2
    STAGE(3, 1); SB0; LOADA(3, Ab0, Ab1); SB0;
    COMPUTE(0, Aa0, Aa1); FENCE8;
    // kt=3
    STAGE(4, 0); SB0; LOADA(4, Aa0, Aa1); SB0;
    COMPUTE(1, Ab0, Ab1); FENCE8;
    // kt=4
    STAGE(5, 1); SB0; LOADA(5, Ab0, Ab1); SB0;
    COMPUTE(0, Aa0, Aa1); FENCE8;
    // kt=5
    STAGE(6, 0); SB0; LOADA(6, Aa0, Aa1); SB0;
    COMPUTE(1, Ab0, Ab1); FENCE8;
    // kt=6
    STAGE(7, 1); SB0; LOADA(7, Ab0, Ab1); SB0;
    COMPUTE(0, Aa0, Aa1); FENCE8;
    // kt=7 (no stage, no trailing barrier)
    COMPUTE(1, Ab0, Ab1);
#undef FENCE8
#undef COMPUTE
#undef LOADA
#undef STAGE
#undef SB0
  }

  // epilogue: C layout col=l31 (unit), row=(r&3)+8*(r>>2)+4*lh
  const int u = u0 + l31;
#pragma unroll
  for (int r = 0; r < 16; ++r) {
    const int m = m0 + (r & 3) + 8 * (r >> 2) + 4 * lh;
    const int tk = tok[m];
    const float* Erow = E + (size_t)tk * G4;
    const float gi = acc[0][r] + Erow[u];
    const float gf = acc[1][r] + Erow[HID + u];
    const float gg = acc[2][r] + Erow[2 * HID + u];
    const float go = acc[3][r] + Erow[3 * HID + u];
    const float si = 1.f / (1.f + expf(-gi));
    const float sf = 1.f / (1.f + expf(-gf));
    const float so = 1.f / (1.f + expf(-go));
    const size_t ci = (size_t)m * HID + u;
    const float cv = zh ? 0.f : c[ci];
    const float nc = sf * cv + si * tanhf(gg);
    const float hv = so * tanhf(nc);
    c[ci] = nc;
    h_out[ci] = hv;
    ushort hi, lo;
    bf16split(hv, hi, lo);
    const size_t fo = ((size_t)(m >> 5) * 64 + (u >> 3)) * 256 + (size_t)(m & 31) * 8 + (u & 7);
    hf_out[fo] = hi;
    hf_out[HF + fo] = lo;
  }
}

// ---------------- logits + softmax + categorical sample ----------------
// 512 blocks x 256 thr; wave rg handles rows b0..b0+1 (8 rows/block).
__global__ __launch_bounds__(256) void logits2(
    const float* __restrict__ h, const float* __restrict__ wlt,
    const float* __restrict__ b_lin, float* __restrict__ out,
    int* __restrict__ tok, int step)
{
  const int tid = threadIdx.x;
  const int o = tid & 63;
  const int rg = tid >> 6;
  const int b0 = blockIdx.x * 8 + rg * 2;
  float acc0 = 0.f, acc1 = 0.f;
  const float* h0 = h + (size_t)b0 * HID;
  const float* h1 = h0 + HID;
#pragma unroll 4
  for (int k4 = 0; k4 < 128; ++k4) {
    const float4 wv = *(const float4*)(wlt + (size_t)(k4 * 64 + o) * 4);
    const float4 x0 = *(const float4*)(h0 + k4 * 4);
    const float4 x1 = *(const float4*)(h1 + k4 * 4);
    acc0 += wv.x * x0.x + wv.y * x0.y + wv.z * x0.z + wv.w * x0.w;
    acc1 += wv.x * x1.x + wv.y * x1.y + wv.z * x1.z + wv.w * x1.w;
  }
  const float bl = b_lin[o];
  uint32_t s0, s1;
  tf2x32(0u, 42u, 0u, (uint32_t)step, s0, s1);
  float lg[2] = {acc0 + bl, acc1 + bl};
#pragma unroll
  for (int r = 0; r < 2; ++r) {
    const int b = b0 + r;
    const float logit = lg[r];
    float mx = logit;
#pragma unroll
    for (int d = 32; d; d >>= 1) mx = fmaxf(mx, __shfl_xor(mx, d));
    float e = expf(logit - mx);
    float ssum = e;
#pragma unroll
    for (int d = 32; d; d >>= 1) ssum += __shfl_xor(ssum, d);
    out[((size_t)b * STEPS + step) * NOUT + o] = e / ssum;

    uint32_t r0, r1;
    tf2x32(s0, s1, 0u, (uint32_t)(b * NOUT + o), r0, r1);
    const uint32_t bits = r0 ^ r1;
    float uu = __uint_as_float((bits >> 9) | 0x3f800000u) - 1.0f;
    uu = fmaxf(uu, 1.17549435e-38f);
    const float gmb = -logf(-logf(uu));
    float v = logit + gmb;
    int bi = o;
#pragma unroll
    for (int d = 32; d; d >>= 1) {
      float ov = __shfl_xor(v, d);
      int oi = __shfl_xor(bi, d);
      if (ov > v || (ov == v && oi < bi)) { v = ov; bi = oi; }
    }
    if (o == 0) tok[b] = bi;
  }
}

// ---------------- host ----------------
extern "C" void kernel_launch(void* const* d_in, const int* in_sizes, int n_in,
                              void* d_out, int out_size, void* d_ws, size_t ws_size,
                              hipStream_t stream) {
  const int*   x     = (const int*)d_in[0];
  const float* emb   = (const float*)d_in[1];
  const float* W_ih  = (const float*)d_in[2];
  const float* W_hh  = (const float*)d_in[3];
  const float* b_ih  = (const float*)d_in[4];
  const float* b_hh  = (const float*)d_in[5];
  const float* W_lin = (const float*)d_in[6];
  const float* b_lin = (const float*)d_in[7];
  float* out = (float*)d_out;

  float*  E    = (float*)d_ws;              // 131072 f32
  float*  c    = E + 131072;                // 2M f32
  float*  h    = c + HF;                    // 2M f32
  float*  wlt  = h + HF;                    // 32768 f32
  ushort* hf0  = (ushort*)(wlt + 32768);    // 2 planes x 2M u16
  ushort* hf1  = hf0 + 2 * HF;
  ushort* wswz = hf1 + 2 * HF;              // 2M u16
  int*    tok  = (int*)(wswz + 2097152);

  eproj_kernel<<<64, 256, 0, stream>>>(emb, W_ih, b_ih, b_hh, E);
  wprep_whh<<<1024, 256, 0, stream>>>(W_hh, wswz);
  wprep_lin<<<128, 256, 0, stream>>>(W_lin, wlt);

  const int* cur_tok = x;
  ushort* hfin = hf0;
  ushort* hfout = hf1;
  for (int t = 0; t < STEPS; ++t) {
    lstm_step_mfma<<<256, 512, 0, stream>>>(hfin, c, h, hfout, wswz, E, cur_tok, t == 0);
    logits2<<<512, 256, 0, stream>>>(h, wlt, b_lin, out, tok, t);
    cur_tok = tok;
    ushort* tmp = hfin; hfin = hfout; hfout = tmp;
  }
}